// Round 1
// baseline (859.822 us; speedup 1.0000x reference)
//
#include <hip/hip_runtime.h>
#include <math.h>

#define B_    4096
#define S_    50
#define HID_  256
#define NH_   4
#define HD_   64
#define FB_   26
#define NPAIR 25

// ---------------------------------------------------------------------------
// P0: fold base_filter/base_bias/b2/w2 + inverse-DFT cosine weights into a
// single matrix Wp[256][400] and constant C0[400].
// Output layout m = h*100 + cls*50 + tau   (cls 0 = conv kernel c, 1 = bias v)
// ---------------------------------------------------------------------------
__global__ void precompute_kernel(const float* __restrict__ base_filter,
                                  const float* __restrict__ base_bias,
                                  const float* __restrict__ w2,
                                  const float* __restrict__ b2,
                                  float* __restrict__ Wp,
                                  float* __restrict__ C0)
{
    const int m   = blockIdx.x;      // 0..399
    const int j   = threadIdx.x;     // 0..255
    const int h   = m / 100;
    const int rem = m % 100;
    const int cls = rem / 50;
    const int tau = rem % 50;

    const float inv50  = 1.0f / 50.0f;
    const float invs50 = 0.141421356237309515f;  // 1/sqrt(50)

    float acc   = 0.0f;
    float c0acc = 0.0f;
    for (int k = 0; k < FB_; ++k) {
        int   mm   = (k * tau) % 50;
        float cosv = cospif((float)(2 * mm) / 50.0f);
        float wk   = (k == 0 || k == 25) ? 1.0f : 2.0f;
        int   o    = (h * FB_ + k) * 2 + cls;
        float coef;
        if (cls == 0) coef = wk * inv50 * cosv * base_filter[h * FB_ + k];
        else          coef = wk * invs50 * cosv;
        acc += coef * w2[j * 208 + o];
        if (j == 0) {
            if (cls == 0) c0acc += coef * (1.0f + b2[o]);
            else          c0acc += coef * (base_bias[h * FB_ + k] + b2[o]);
        }
    }
    Wp[j * 400 + m] = acc;
    if (j == 0) C0[m] = c0acc;
}

// ---------------------------------------------------------------------------
// K1: ctx[b,i] = mean over s of attr[b,s,i]
// ---------------------------------------------------------------------------
__global__ __launch_bounds__(256)
void mean_kernel(const float* __restrict__ attr, float* __restrict__ ctx)
{
    const int b = blockIdx.x;
    const int i = threadIdx.x;
    const float* p = attr + (size_t)b * S_ * HID_ + i;
    float s = 0.0f;
    #pragma unroll
    for (int t = 0; t < S_; ++t) s += p[t * HID_];
    ctx[b * HID_ + i] = s * (1.0f / S_);
}

// ---------------------------------------------------------------------------
// Tiled f32 GEMM  C[M,N] = A[M,K] @ B[K,N] (+bias, optional exact-gelu)
// BM=64 BN=64 BK=32, 256 threads, 4x4 microtile. EPI: 0 = gelu(acc+bias),
// 1 = acc+bias.
// ---------------------------------------------------------------------------
template <int EPI>
__global__ __launch_bounds__(256)
void gemm_kernel(const float* __restrict__ A, const float* __restrict__ Bm,
                 const float* __restrict__ bias, float* __restrict__ C,
                 int M, int N, int K)
{
    __shared__ float As[64][33];
    __shared__ float Bs[32][64];
    const int tid = threadIdx.x;
    const int tx = tid & 15, ty = tid >> 4;
    const int col0 = blockIdx.x * 64;
    const int row0 = blockIdx.y * 64;

    float acc[4][4] = {};

    for (int k0 = 0; k0 < K; k0 += 32) {
        #pragma unroll
        for (int l = 0; l < 2; ++l) {
            int f = tid + l * 256;          // 0..511
            int r = f >> 3;
            int c4 = f & 7;
            float4 av = *(const float4*)(A + (size_t)(row0 + r) * K + k0 + c4 * 4);
            As[r][c4 * 4 + 0] = av.x; As[r][c4 * 4 + 1] = av.y;
            As[r][c4 * 4 + 2] = av.z; As[r][c4 * 4 + 3] = av.w;
        }
        #pragma unroll
        for (int l = 0; l < 2; ++l) {
            int f = tid + l * 256;
            int kr = f >> 4;
            int c4 = f & 15;
            int col = col0 + c4 * 4;
            float4 bv = make_float4(0.f, 0.f, 0.f, 0.f);
            if (col < N) bv = *(const float4*)(Bm + (size_t)(k0 + kr) * N + col);
            *(float4*)&Bs[kr][c4 * 4] = bv;
        }
        __syncthreads();
        #pragma unroll
        for (int kk = 0; kk < 32; ++kk) {
            float4 bv = *(float4*)&Bs[kk][tx * 4];
            float br[4] = {bv.x, bv.y, bv.z, bv.w};
            #pragma unroll
            for (int r = 0; r < 4; ++r) {
                float av = As[ty * 4 + r][kk];
                #pragma unroll
                for (int c = 0; c < 4; ++c)
                    acc[r][c] = fmaf(av, br[c], acc[r][c]);
            }
        }
        __syncthreads();
    }

    #pragma unroll
    for (int r = 0; r < 4; ++r) {
        int row = row0 + ty * 4 + r;
        #pragma unroll
        for (int c = 0; c < 4; ++c) {
            int col = col0 + tx * 4 + c;
            if (col < N) {
                float v = acc[r][c] + bias[col];
                if (EPI == 0)
                    v = 0.5f * v * (1.0f + erff(v * 0.70710678118654752f));
                C[(size_t)row * N + col] = v;
            }
        }
    }
}

// ---------------------------------------------------------------------------
// K5: fused circular-conv (spectral path) + wavelet + combine + residual + LN.
// One block per b; thread tid owns column i = tid (head h = tid>>6, d = tid&63).
// cv layout: [b][h][cls][tau], cls 0 = conv kernel c, 1 = additive v[t].
// ---------------------------------------------------------------------------
__global__ __launch_bounds__(256)
void fused_kernel(const float* __restrict__ item,
                  const float* __restrict__ cw,     // (NH,25,64)
                  const float* __restrict__ cv,     // (B,400)
                  const float* __restrict__ gamma,
                  const float* __restrict__ beta,
                  float* __restrict__ out)
{
    __shared__ float lds[S_][260];   // res rows, padded (1040B row = 16B-aligned)

    const int b   = blockIdx.x;
    const int tid = threadIdx.x;
    const int h   = __builtin_amdgcn_readfirstlane(tid >> 6);  // wave-uniform head
    const int d   = tid & 63;

    // conv kernel c (wave-uniform -> scalar loads) issued first
    const float* cb = cv + (size_t)b * 400 + h * 100;
    float cvals[S_];
    #pragma unroll
    for (int j = 0; j < S_; ++j) cvals[j] = cb[j];

    // load this thread's column of x_heads
    const float* xp = item + (size_t)b * S_ * HID_ + tid;
    float x[S_];
    #pragma unroll
    for (int t = 0; t < S_; ++t) x[t] = xp[t * HID_];

    // circular convolution: xfft[t] = sum_tp c[(t-tp)%50] * x[tp]
    float acc[S_];
    #pragma unroll
    for (int t = 0; t < S_; ++t) acc[t] = 0.0f;
    #pragma unroll
    for (int tp = 0; tp < S_; ++tp) {
        float xv = x[tp];
        #pragma unroll
        for (int t = 0; t < S_; ++t) {
            int ci = t - tp; if (ci < 0) ci += S_;
            acc[t] = fmaf(cvals[ci], xv, acc[t]);
        }
    }

    // + v[t], wavelet, combine, residual
    const float* vb  = cb + 50;
    const float* cwp = cw + (size_t)(h * NPAIR) * HD_ + d;
    #pragma unroll
    for (int p = 0; p < NPAIR; ++p) {
        float e = x[2 * p], o = x[2 * p + 1];
        float a  = 0.5f * (e + o);
        float dt = 0.5f * (e - o) * cwp[p * HD_];
        float xf_e = acc[2 * p]     + vb[2 * p];
        float xf_o = acc[2 * p + 1] + vb[2 * p + 1];
        acc[2 * p]     = 0.7f * (a + dt) + 0.3f * xf_e + e;
        acc[2 * p + 1] = 0.7f * (a - dt) + 0.3f * xf_o + o;
    }

    // stage res rows in LDS for row-wise LayerNorm
    #pragma unroll
    for (int t = 0; t < S_; ++t) lds[t][tid] = acc[t];
    __syncthreads();

    // wave w handles rows t = w, w+4, ... ; lane holds 4 consecutive columns
    const int lane = d;
    float4 g4  = *(const float4*)(gamma + lane * 4);
    float4 bt4 = *(const float4*)(beta  + lane * 4);
    for (int t = h; t < S_; t += 4) {
        float4 v4 = *(const float4*)&lds[t][lane * 4];
        float s  = v4.x + v4.y + v4.z + v4.w;
        float sq = v4.x * v4.x + v4.y * v4.y + v4.z * v4.z + v4.w * v4.w;
        #pragma unroll
        for (int m = 1; m < 64; m <<= 1) {
            s  += __shfl_xor(s,  m, 64);
            sq += __shfl_xor(sq, m, 64);
        }
        float mu  = s * (1.0f / HID_);
        float var = sq * (1.0f / HID_) - mu * mu;
        float rs  = rsqrtf(var + 1e-12f);
        float4 o4;
        o4.x = (v4.x - mu) * rs * g4.x + bt4.x;
        o4.y = (v4.y - mu) * rs * g4.y + bt4.y;
        o4.z = (v4.z - mu) * rs * g4.z + bt4.z;
        o4.w = (v4.w - mu) * rs * g4.w + bt4.w;
        *(float4*)(out + (size_t)b * S_ * HID_ + (size_t)t * HID_ + lane * 4) = o4;
    }
}

// ---------------------------------------------------------------------------
extern "C" void kernel_launch(void* const* d_in, const int* in_sizes, int n_in,
                              void* d_out, int out_size, void* d_ws, size_t ws_size,
                              hipStream_t stream)
{
    (void)in_sizes; (void)n_in; (void)out_size; (void)ws_size;
    const float* item = (const float*)d_in[0];
    const float* attr = (const float*)d_in[1];
    const float* cw   = (const float*)d_in[2];
    const float* bf   = (const float*)d_in[3];
    const float* bb   = (const float*)d_in[4];
    const float* w1   = (const float*)d_in[5];
    const float* b1   = (const float*)d_in[6];
    const float* w2   = (const float*)d_in[7];
    const float* b2   = (const float*)d_in[8];
    const float* g    = (const float*)d_in[9];
    const float* be   = (const float*)d_in[10];
    float* out = (float*)d_out;
    float* ws  = (float*)d_ws;

    float* ctx  = ws;              // 4096*256   = 1,048,576 f
    float* hbuf = ws + 1048576;    // 4096*256   = 1,048,576 f
    float* Wp   = ws + 2097152;    // 256*400    =   102,400 f
    float* C0   = ws + 2199552;    //               400 f
    float* cvb  = ws + 2200064;    // 4096*400   = 1,638,400 f  (~15.4 MB total)

    hipLaunchKernelGGL(precompute_kernel, dim3(400), dim3(256), 0, stream,
                       bf, bb, w2, b2, Wp, C0);
    hipLaunchKernelGGL(mean_kernel, dim3(B_), dim3(256), 0, stream, attr, ctx);
    hipLaunchKernelGGL((gemm_kernel<0>), dim3(4, 64), dim3(256), 0, stream,
                       ctx, w1, b1, hbuf, B_, 256, 256);
    hipLaunchKernelGGL((gemm_kernel<1>), dim3(7, 64), dim3(256), 0, stream,
                       hbuf, Wp, C0, cvb, B_, 400, 256);
    hipLaunchKernelGGL(fused_kernel, dim3(B_), dim3(256), 0, stream,
                       item, cw, cvb, g, be, out);
}

// Round 2
// 846.139 us; speedup vs baseline: 1.0162x; 1.0162x over previous
//
#include <hip/hip_runtime.h>
#include <math.h>

#define B_    4096
#define S_    50
#define HID_  256
#define NH_   4
#define HD_   64
#define FB_   26
#define NPAIR 25

// ---------------------------------------------------------------------------
// P0: fold base_filter/base_bias/b2/w2 + inverse-DFT cosine weights into a
// single matrix Wp[256][400] and constant C0[400].
// Output layout m = h*100 + cls*50 + tau   (cls 0 = conv kernel c, 1 = bias v)
// Note c[tau] == c[50-tau] (real symmetric spectrum) -> fused kernel reads
// only tau=0..25 of cls 0.
// ---------------------------------------------------------------------------
__global__ void precompute_kernel(const float* __restrict__ base_filter,
                                  const float* __restrict__ base_bias,
                                  const float* __restrict__ w2,
                                  const float* __restrict__ b2,
                                  float* __restrict__ Wp,
                                  float* __restrict__ C0)
{
    const int m   = blockIdx.x;      // 0..399
    const int j   = threadIdx.x;     // 0..255
    const int h   = m / 100;
    const int rem = m % 100;
    const int cls = rem / 50;
    const int tau = rem % 50;

    const float inv50  = 1.0f / 50.0f;
    const float invs50 = 0.141421356237309515f;  // 1/sqrt(50)

    float acc   = 0.0f;
    float c0acc = 0.0f;
    for (int k = 0; k < FB_; ++k) {
        int   mm   = (k * tau) % 50;
        float cosv = cospif((float)(2 * mm) / 50.0f);
        float wk   = (k == 0 || k == 25) ? 1.0f : 2.0f;
        int   o    = (h * FB_ + k) * 2 + cls;
        float coef;
        if (cls == 0) coef = wk * inv50 * cosv * base_filter[h * FB_ + k];
        else          coef = wk * invs50 * cosv;
        acc += coef * w2[j * 208 + o];
        if (j == 0) {
            if (cls == 0) c0acc += coef * (1.0f + b2[o]);
            else          c0acc += coef * (base_bias[h * FB_ + k] + b2[o]);
        }
    }
    Wp[j * 400 + m] = acc;
    if (j == 0) C0[m] = c0acc;
}

// ---------------------------------------------------------------------------
// K1: ctx[b,i] = mean over s of attr[b,s,i]  (float4 vectorized, 4 rows/block)
// ---------------------------------------------------------------------------
__global__ __launch_bounds__(256)
void mean_kernel(const float* __restrict__ attr, float* __restrict__ ctx)
{
    const int g    = threadIdx.x >> 6;          // 0..3 : which b this wave owns
    const int lane = threadIdx.x & 63;
    const int b    = blockIdx.x * 4 + g;
    const float4* p = (const float4*)(attr + (size_t)b * S_ * HID_) + lane;
    float4 s = make_float4(0.f, 0.f, 0.f, 0.f);
    #pragma unroll
    for (int t = 0; t < S_; ++t) {
        float4 v = p[t * 64];
        s.x += v.x; s.y += v.y; s.z += v.z; s.w += v.w;
    }
    const float is = 1.0f / S_;
    s.x *= is; s.y *= is; s.z *= is; s.w *= is;
    ((float4*)(ctx + (size_t)b * HID_))[lane] = s;
}

// ---------------------------------------------------------------------------
// Tiled f32 GEMM  C[M,N] = A[M,K] @ B[K,N] (+bias, optional exact-gelu)
// BM=64 BN=64 BK=32, 256 threads, 4x4 microtile.
// ---------------------------------------------------------------------------
template <int EPI>
__global__ __launch_bounds__(256)
void gemm_kernel(const float* __restrict__ A, const float* __restrict__ Bm,
                 const float* __restrict__ bias, float* __restrict__ C,
                 int M, int N, int K)
{
    __shared__ float As[64][33];
    __shared__ float Bs[32][64];
    const int tid = threadIdx.x;
    const int tx = tid & 15, ty = tid >> 4;
    const int col0 = blockIdx.x * 64;
    const int row0 = blockIdx.y * 64;

    float acc[4][4] = {};

    for (int k0 = 0; k0 < K; k0 += 32) {
        #pragma unroll
        for (int l = 0; l < 2; ++l) {
            int f = tid + l * 256;
            int r = f >> 3;
            int c4 = f & 7;
            float4 av = *(const float4*)(A + (size_t)(row0 + r) * K + k0 + c4 * 4);
            As[r][c4 * 4 + 0] = av.x; As[r][c4 * 4 + 1] = av.y;
            As[r][c4 * 4 + 2] = av.z; As[r][c4 * 4 + 3] = av.w;
        }
        #pragma unroll
        for (int l = 0; l < 2; ++l) {
            int f = tid + l * 256;
            int kr = f >> 4;
            int c4 = f & 15;
            int col = col0 + c4 * 4;
            float4 bv = make_float4(0.f, 0.f, 0.f, 0.f);
            if (col < N) bv = *(const float4*)(Bm + (size_t)(k0 + kr) * N + col);
            *(float4*)&Bs[kr][c4 * 4] = bv;
        }
        __syncthreads();
        #pragma unroll
        for (int kk = 0; kk < 32; ++kk) {
            float4 bv = *(float4*)&Bs[kk][tx * 4];
            float br[4] = {bv.x, bv.y, bv.z, bv.w};
            #pragma unroll
            for (int r = 0; r < 4; ++r) {
                float av = As[ty * 4 + r][kk];
                #pragma unroll
                for (int c = 0; c < 4; ++c)
                    acc[r][c] = fmaf(av, br[c], acc[r][c]);
            }
        }
        __syncthreads();
    }

    #pragma unroll
    for (int r = 0; r < 4; ++r) {
        int row = row0 + ty * 4 + r;
        #pragma unroll
        for (int c = 0; c < 4; ++c) {
            int col = col0 + tx * 4 + c;
            if (col < N) {
                float v = acc[r][c] + bias[col];
                if (EPI == 0)
                    v = 0.5f * v * (1.0f + erff(v * 0.70710678118654752f));
                C[(size_t)row * N + col] = v;
            }
        }
    }
}

// ---------------------------------------------------------------------------
// K5: fused circular-conv + wavelet + combine + residual + LayerNorm.
// One block per b; thread tid owns column i (head h = tid>>6, d = tid&63).
// Two row-chunks (rows 0..25, 26..49) keep live VGPRs ~100 -> no spills.
// LayerNorm: 64-lane shfl butterfly + 4-wave LDS partials (1.7 KB LDS total).
// cv layout: [b][h][cls][tau]; c symmetric -> only c[0..25] read.
// ---------------------------------------------------------------------------
__global__ __launch_bounds__(256, 4)
void fused_kernel(const float* __restrict__ item,
                  const float* __restrict__ cw,     // (NH,25,64)
                  const float* __restrict__ cv,     // (B,400)
                  const float* __restrict__ gamma,
                  const float* __restrict__ beta,
                  float* __restrict__ out)
{
    __shared__ float part[2][26][4][2];   // [chunk][row][wave][{s,sq}]

    const int b    = blockIdx.x;
    const int tid  = threadIdx.x;
    const int w    = __builtin_amdgcn_readfirstlane(tid >> 6);  // wave id == head
    const int lane = tid & 63;

    // wave-uniform conv-kernel/bias base -> scalar loads
    const float* cb = cv + (size_t)b * 400 + w * 100;
    float cvals[26];
    #pragma unroll
    for (int j = 0; j < 26; ++j) cvals[j] = cb[j];
    const float* vb = cb + 50;

    // this thread's column of x_heads
    const float* xp = item + (size_t)b * S_ * HID_ + tid;
    float x[S_];
    #pragma unroll
    for (int t = 0; t < S_; ++t) x[t] = xp[t * HID_];

    const float gam = gamma[tid];
    const float bet = beta[tid];
    float* outp = out + (size_t)b * S_ * HID_ + tid;
    const float* cwp = cw + (size_t)(w * NPAIR) * HD_ + lane;

    #pragma unroll
    for (int ck = 0; ck < 2; ++ck) {
        const int base  = (ck == 0) ? 0 : 26;   // first row of chunk
        const int nrows = (ck == 0) ? 26 : 24;
        const int p0    = base / 2;             // first wavelet pair
        const int np    = nrows / 2;

        // ---- circular conv for rows [base, base+nrows) ----
        float acc[26];
        #pragma unroll
        for (int j = 0; j < 26; ++j) acc[j] = 0.0f;
        #pragma unroll
        for (int tp = 0; tp < S_; ++tp) {
            const float xv = x[tp];
            #pragma unroll
            for (int j = 0; j < 26; ++j) {
                if (j < nrows) {
                    int ci = base + j - tp; if (ci < 0) ci += S_;
                    int dd = (ci > 25) ? (S_ - ci) : ci;
                    acc[j] = fmaf(cvals[dd], xv, acc[j]);
                }
            }
        }

        // ---- + v, wavelet, combine, residual ----
        #pragma unroll
        for (int q = 0; q < 13; ++q) {
            if (q < np) {
                const int p  = p0 + q;          // global pair index
                const int j  = 2 * q;           // chunk-local even row
                float e = x[2 * p], o = x[2 * p + 1];
                float a  = 0.5f * (e + o);
                float dt = 0.5f * (e - o) * cwp[p * HD_];
                float fe = acc[j]     + vb[2 * p];
                float fo = acc[j + 1] + vb[2 * p + 1];
                acc[j]     = 0.7f * (a + dt) + 0.3f * fe + e;
                acc[j + 1] = 0.7f * (a - dt) + 0.3f * fo + o;
            }
        }

        // ---- LayerNorm: per-row cross-thread reduction ----
        float ls = 0.0f, lq = 0.0f;
        #pragma unroll
        for (int j = 0; j < 26; ++j) {
            if (j < nrows) {
                float s = acc[j];
                float q = acc[j] * acc[j];
                #pragma unroll
                for (int m = 1; m < 64; m <<= 1) {
                    s += __shfl_xor(s, m, 64);
                    q += __shfl_xor(q, m, 64);
                }
                if (lane == j) { ls = s; lq = q; }
            }
        }
        if (lane < nrows) {
            part[ck][lane][w][0] = ls;
            part[ck][lane][w][1] = lq;
        }
        __syncthreads();

        #pragma unroll
        for (int j = 0; j < 26; ++j) {
            if (j < nrows) {
                float4 pa = *(const float4*)&part[ck][j][0][0];
                float4 pb = *(const float4*)&part[ck][j][2][0];
                float s  = (pa.x + pa.z) + (pb.x + pb.z);
                float qq = (pa.y + pa.w) + (pb.y + pb.w);
                float mu  = s * (1.0f / HID_);
                float var = qq * (1.0f / HID_) - mu * mu;
                float rs  = rsqrtf(var + 1e-12f);
                outp[(base + j) * HID_] = (acc[j] - mu) * rs * gam + bet;
            }
        }
    }
}

// ---------------------------------------------------------------------------
extern "C" void kernel_launch(void* const* d_in, const int* in_sizes, int n_in,
                              void* d_out, int out_size, void* d_ws, size_t ws_size,
                              hipStream_t stream)
{
    (void)in_sizes; (void)n_in; (void)out_size; (void)ws_size;
    const float* item = (const float*)d_in[0];
    const float* attr = (const float*)d_in[1];
    const float* cw   = (const float*)d_in[2];
    const float* bf   = (const float*)d_in[3];
    const float* bb   = (const float*)d_in[4];
    const float* w1   = (const float*)d_in[5];
    const float* b1   = (const float*)d_in[6];
    const float* w2   = (const float*)d_in[7];
    const float* b2   = (const float*)d_in[8];
    const float* g    = (const float*)d_in[9];
    const float* be   = (const float*)d_in[10];
    float* out = (float*)d_out;
    float* ws  = (float*)d_ws;

    float* ctx  = ws;              // 4096*256
    float* hbuf = ws + 1048576;    // 4096*256
    float* Wp   = ws + 2097152;    // 256*400
    float* C0   = ws + 2199552;    // 400
    float* cvb  = ws + 2200064;    // 4096*400

    hipLaunchKernelGGL(precompute_kernel, dim3(400), dim3(256), 0, stream,
                       bf, bb, w2, b2, Wp, C0);
    hipLaunchKernelGGL(mean_kernel, dim3(B_ / 4), dim3(256), 0, stream, attr, ctx);
    hipLaunchKernelGGL((gemm_kernel<0>), dim3(4, 64), dim3(256), 0, stream,
                       ctx, w1, b1, hbuf, B_, 256, 256);
    hipLaunchKernelGGL((gemm_kernel<1>), dim3(7, 64), dim3(256), 0, stream,
                       hbuf, Wp, C0, cvb, B_, 400, 256);
    hipLaunchKernelGGL(fused_kernel, dim3(B_), dim3(256), 0, stream,
                       item, cw, cvb, g, be, out);
}

// Round 4
// 668.861 us; speedup vs baseline: 1.2855x; 1.2650x over previous
//
#include <hip/hip_runtime.h>
#include <math.h>
#include <utility>

#define B_    4096
#define S_    50
#define HID_  256
#define NH_   4
#define HD_   64
#define FB_   26
#define NPAIR 25
#define CHUNK 10

// float-safe readfirstlane (the builtin is int(int); raw use on float
// TRUNCATES — round-3 bug).
__device__ __forceinline__ float rfl_f(float v) {
    union { float f; int i; } u;
    u.f = v;
    u.i = __builtin_amdgcn_readfirstlane(u.i);
    return u.f;
}

// ---------------------------------------------------------------------------
// P0: fold base_filter/base_bias/b2/w2 + inverse-DFT cosine weights into a
// single matrix Wp[256][400] and constant C0[400].
// m = h*100 + cls*50 + tau ; cls 0 = conv kernel c (c[tau]==c[50-tau]),
// cls 1 = additive bias v[t].
// ---------------------------------------------------------------------------
__global__ void precompute_kernel(const float* __restrict__ base_filter,
                                  const float* __restrict__ base_bias,
                                  const float* __restrict__ w2,
                                  const float* __restrict__ b2,
                                  float* __restrict__ Wp,
                                  float* __restrict__ C0)
{
    const int m   = blockIdx.x;      // 0..399
    const int j   = threadIdx.x;     // 0..255
    const int h   = m / 100;
    const int rem = m % 100;
    const int cls = rem / 50;
    const int tau = rem % 50;

    const float inv50  = 1.0f / 50.0f;
    const float invs50 = 0.141421356237309515f;  // 1/sqrt(50)

    float acc   = 0.0f;
    float c0acc = 0.0f;
    for (int k = 0; k < FB_; ++k) {
        int   mm   = (k * tau) % 50;
        float cosv = cospif((float)(2 * mm) / 50.0f);
        float wk   = (k == 0 || k == 25) ? 1.0f : 2.0f;
        int   o    = (h * FB_ + k) * 2 + cls;
        float coef;
        if (cls == 0) coef = wk * inv50 * cosv * base_filter[h * FB_ + k];
        else          coef = wk * invs50 * cosv;
        acc += coef * w2[j * 208 + o];
        if (j == 0) {
            if (cls == 0) c0acc += coef * (1.0f + b2[o]);
            else          c0acc += coef * (base_bias[h * FB_ + k] + b2[o]);
        }
    }
    Wp[j * 400 + m] = acc;
    if (j == 0) C0[m] = c0acc;
}

// ---------------------------------------------------------------------------
// K1: ctx[b,i] = mean over s of attr[b,s,i]  (float4, 4 rows/block)
// ---------------------------------------------------------------------------
__global__ __launch_bounds__(256)
void mean_kernel(const float* __restrict__ attr, float* __restrict__ ctx)
{
    const int g    = threadIdx.x >> 6;
    const int lane = threadIdx.x & 63;
    const int b    = blockIdx.x * 4 + g;
    const float4* p = (const float4*)(attr + (size_t)b * S_ * HID_) + lane;
    float4 s = make_float4(0.f, 0.f, 0.f, 0.f);
    #pragma unroll
    for (int t = 0; t < S_; ++t) {
        float4 v = p[t * 64];
        s.x += v.x; s.y += v.y; s.z += v.z; s.w += v.w;
    }
    const float is = 1.0f / S_;
    s.x *= is; s.y *= is; s.z *= is; s.w *= is;
    ((float4*)(ctx + (size_t)b * HID_))[lane] = s;
}

// ---------------------------------------------------------------------------
// Tiled f32 GEMM  C[M,N] = A[M,K] @ B[K,N] (+bias, optional exact-gelu)
// ---------------------------------------------------------------------------
template <int EPI>
__global__ __launch_bounds__(256)
void gemm_kernel(const float* __restrict__ A, const float* __restrict__ Bm,
                 const float* __restrict__ bias, float* __restrict__ C,
                 int M, int N, int K)
{
    __shared__ float As[64][33];
    __shared__ float Bs[32][64];
    const int tid = threadIdx.x;
    const int tx = tid & 15, ty = tid >> 4;
    const int col0 = blockIdx.x * 64;
    const int row0 = blockIdx.y * 64;

    float acc[4][4] = {};

    for (int k0 = 0; k0 < K; k0 += 32) {
        #pragma unroll
        for (int l = 0; l < 2; ++l) {
            int f = tid + l * 256;
            int r = f >> 3;
            int c4 = f & 7;
            float4 av = *(const float4*)(A + (size_t)(row0 + r) * K + k0 + c4 * 4);
            As[r][c4 * 4 + 0] = av.x; As[r][c4 * 4 + 1] = av.y;
            As[r][c4 * 4 + 2] = av.z; As[r][c4 * 4 + 3] = av.w;
        }
        #pragma unroll
        for (int l = 0; l < 2; ++l) {
            int f = tid + l * 256;
            int kr = f >> 4;
            int c4 = f & 15;
            int col = col0 + c4 * 4;
            float4 bv = make_float4(0.f, 0.f, 0.f, 0.f);
            if (col < N) bv = *(const float4*)(Bm + (size_t)(k0 + kr) * N + col);
            *(float4*)&Bs[kr][c4 * 4] = bv;
        }
        __syncthreads();
        #pragma unroll
        for (int kk = 0; kk < 32; ++kk) {
            float4 bv = *(float4*)&Bs[kk][tx * 4];
            float br[4] = {bv.x, bv.y, bv.z, bv.w};
            #pragma unroll
            for (int r = 0; r < 4; ++r) {
                float av = As[ty * 4 + r][kk];
                #pragma unroll
                for (int c = 0; c < 4; ++c)
                    acc[r][c] = fmaf(av, br[c], acc[r][c]);
            }
        }
        __syncthreads();
    }

    #pragma unroll
    for (int r = 0; r < 4; ++r) {
        int row = row0 + ty * 4 + r;
        #pragma unroll
        for (int c = 0; c < 4; ++c) {
            int col = col0 + tx * 4 + c;
            if (col < N) {
                float v = acc[r][c] + bias[col];
                if (EPI == 0)
                    v = 0.5f * v * (1.0f + erff(v * 0.70710678118654752f));
                C[(size_t)row * N + col] = v;
            }
        }
    }
}

// ---------------------------------------------------------------------------
// Compile-time-indexed circular conv helpers: every array index is a
// constexpr so x[], a[], cv[] are guaranteed register-resident (no scratch).
// ---------------------------------------------------------------------------
template <int T, int TP>
__device__ __forceinline__ float cval(const float (&cv)[26]) {
    constexpr int ci = ((T - TP) % 50 + 50) % 50;
    constexpr int dd = (ci > 25) ? (50 - ci) : ci;
    return cv[dd];
}

template <int R0, int TP, int... J>
__device__ __forceinline__ void convJ(float (&a)[CHUNK], const float (&x)[50],
                                      const float (&cv)[26],
                                      std::integer_sequence<int, J...>) {
    ((a[J] = fmaf(cval<R0 + J, TP>(cv), x[TP], a[J])), ...);
}

template <int R0, int... TPs>
__device__ __forceinline__ void convChunk(float (&a)[CHUNK], const float (&x)[50],
                                          const float (&cv)[26],
                                          std::integer_sequence<int, TPs...>) {
    (convJ<R0, TPs>(a, x, cv, std::make_integer_sequence<int, CHUNK>{}), ...);
}

// One 10-row chunk: conv + wavelet/combine/residual + LayerNorm + store.
template <int R0>
__device__ __forceinline__ void chunk_proc(const float (&x)[50], const float (&cv)[26],
                                           const float* __restrict__ vb,
                                           const float* __restrict__ cwp,
                                           float gam, float bet,
                                           float* __restrict__ outp,
                                           float (*part)[4][2], int w, int lane)
{
    float a[CHUNK] = {};
    convChunk<R0>(a, x, cv, std::make_integer_sequence<int, 50>{});

    // wavelet + combine + residual (pairs p = R0/2 .. R0/2+4)
    #pragma unroll
    for (int q = 0; q < CHUNK / 2; ++q) {
        const int p = R0 / 2 + q;
        float e  = x[2 * p], o = x[2 * p + 1];
        float ap = 0.5f * (e + o);
        float dt = 0.5f * (e - o) * cwp[p * HD_];
        float ve = rfl_f(vb[2 * p]);
        float vo = rfl_f(vb[2 * p + 1]);
        float fe = a[2 * q]     + ve;
        float fo = a[2 * q + 1] + vo;
        a[2 * q]     = 0.7f * (ap + dt) + 0.3f * fe + e;
        a[2 * q + 1] = 0.7f * (ap - dt) + 0.3f * fo + o;
    }

    // per-row 64-lane butterfly; row j's wave-sum parked in lane j
    float ls = 0.0f, lq = 0.0f;
    #pragma unroll
    for (int j = 0; j < CHUNK; ++j) {
        float s  = a[j];
        float q2 = a[j] * a[j];
        #pragma unroll
        for (int m = 1; m < 64; m <<= 1) {
            s  += __shfl_xor(s,  m, 64);
            q2 += __shfl_xor(q2, m, 64);
        }
        if (lane == j) { ls = s; lq = q2; }
    }
    if (lane < CHUNK) { part[lane][w][0] = ls; part[lane][w][1] = lq; }
    __syncthreads();

    #pragma unroll
    for (int j = 0; j < CHUNK; ++j) {
        float4 pa = *(const float4*)&part[j][0][0];
        float4 pb = *(const float4*)&part[j][2][0];
        float s   = (pa.x + pa.z) + (pb.x + pb.z);
        float qq  = (pa.y + pa.w) + (pb.y + pb.w);
        float mu  = s * (1.0f / HID_);
        float var = qq * (1.0f / HID_) - mu * mu;
        float rs  = rsqrtf(var + 1e-12f);
        outp[(R0 + j) * HID_] = (a[j] - mu) * rs * gam + bet;
    }
}

// ---------------------------------------------------------------------------
// K5: fused circular-conv + wavelet + combine + residual + LayerNorm.
// One block per b; thread tid owns column tid (head = wave id).
// 5 chunks of 10 rows keep live VGPRs ~90; conv coeffs forced to SGPRs.
// ---------------------------------------------------------------------------
__global__ __launch_bounds__(256, 4)
void fused_kernel(const float* __restrict__ item,
                  const float* __restrict__ cw,     // (NH,25,64)
                  const float* __restrict__ cv,     // (B,400)
                  const float* __restrict__ gamma,
                  const float* __restrict__ beta,
                  float* __restrict__ out)
{
    __shared__ float part[5][CHUNK][4][2];   // distinct region per chunk

    const int b    = blockIdx.x;
    const int tid  = threadIdx.x;
    const int w    = tid >> 6;
    const int lane = tid & 63;
    const int wu   = __builtin_amdgcn_readfirstlane(w);

    // wave-uniform conv kernel (symmetric: only tau 0..25) -> SGPRs
    const float* cb = cv + (size_t)b * 400 + wu * 100;
    float cvr[26];
    #pragma unroll
    for (int j = 0; j < 26; ++j)
        cvr[j] = rfl_f(cb[j]);
    const float* vb = cb + 50;

    // this thread's column of x_heads
    const float* xp = item + (size_t)b * S_ * HID_ + tid;
    float x[50];
    #pragma unroll
    for (int t = 0; t < 50; ++t) x[t] = xp[t * HID_];

    const float gam = gamma[tid];
    const float bet = beta[tid];
    float* outp = out + (size_t)b * S_ * HID_ + tid;
    const float* cwp = cw + (size_t)(wu * NPAIR) * HD_ + lane;

    chunk_proc< 0>(x, cvr, vb, cwp, gam, bet, outp, part[0], w, lane);
    chunk_proc<10>(x, cvr, vb, cwp, gam, bet, outp, part[1], w, lane);
    chunk_proc<20>(x, cvr, vb, cwp, gam, bet, outp, part[2], w, lane);
    chunk_proc<30>(x, cvr, vb, cwp, gam, bet, outp, part[3], w, lane);
    chunk_proc<40>(x, cvr, vb, cwp, gam, bet, outp, part[4], w, lane);
}

// ---------------------------------------------------------------------------
extern "C" void kernel_launch(void* const* d_in, const int* in_sizes, int n_in,
                              void* d_out, int out_size, void* d_ws, size_t ws_size,
                              hipStream_t stream)
{
    (void)in_sizes; (void)n_in; (void)out_size; (void)ws_size;
    const float* item = (const float*)d_in[0];
    const float* attr = (const float*)d_in[1];
    const float* cw   = (const float*)d_in[2];
    const float* bf   = (const float*)d_in[3];
    const float* bb   = (const float*)d_in[4];
    const float* w1   = (const float*)d_in[5];
    const float* b1   = (const float*)d_in[6];
    const float* w2   = (const float*)d_in[7];
    const float* b2   = (const float*)d_in[8];
    const float* g    = (const float*)d_in[9];
    const float* be   = (const float*)d_in[10];
    float* out = (float*)d_out;
    float* ws  = (float*)d_ws;

    float* ctx  = ws;              // 4096*256
    float* hbuf = ws + 1048576;    // 4096*256
    float* Wp   = ws + 2097152;    // 256*400
    float* C0   = ws + 2199552;    // 400
    float* cvb  = ws + 2200064;    // 4096*400

    hipLaunchKernelGGL(precompute_kernel, dim3(400), dim3(256), 0, stream,
                       bf, bb, w2, b2, Wp, C0);
    hipLaunchKernelGGL(mean_kernel, dim3(B_ / 4), dim3(256), 0, stream, attr, ctx);
    hipLaunchKernelGGL((gemm_kernel<0>), dim3(4, 64), dim3(256), 0, stream,
                       ctx, w1, b1, hbuf, B_, 256, 256);
    hipLaunchKernelGGL((gemm_kernel<1>), dim3(7, 64), dim3(256), 0, stream,
                       hbuf, Wp, C0, cvb, B_, 400, 256);
    hipLaunchKernelGGL(fused_kernel, dim3(B_), dim3(256), 0, stream,
                       item, cw, cvb, g, be, out);
}

// Round 5
// 590.601 us; speedup vs baseline: 1.4558x; 1.1325x over previous
//
#include <hip/hip_runtime.h>
#include <math.h>
#include <utility>

#define B_    4096
#define S_    50
#define HID_  256
#define NH_   4
#define HD_   64
#define FB_   26
#define NPAIR 25
#define CHUNK 10

// float-safe readfirstlane (the builtin is int(int); raw use on float
// TRUNCATES — round-3 bug).
__device__ __forceinline__ float rfl_f(float v) {
    union { float f; int i; } u;
    u.f = v;
    u.i = __builtin_amdgcn_readfirstlane(u.i);
    return u.f;
}

// ---------------------------------------------------------------------------
// P0: fold base_filter/base_bias/b2/w2 + inverse-DFT cosine weights into a
// single matrix Wp[256][400] and constant C0[400].
// m = h*100 + cls*50 + tau ; cls 0 = conv kernel c (c[tau]==c[50-tau]),
// cls 1 = additive bias v[t].
// ---------------------------------------------------------------------------
__global__ void precompute_kernel(const float* __restrict__ base_filter,
                                  const float* __restrict__ base_bias,
                                  const float* __restrict__ w2,
                                  const float* __restrict__ b2,
                                  float* __restrict__ Wp,
                                  float* __restrict__ C0)
{
    const int m   = blockIdx.x;      // 0..399
    const int j   = threadIdx.x;     // 0..255
    const int h   = m / 100;
    const int rem = m % 100;
    const int cls = rem / 50;
    const int tau = rem % 50;

    const float inv50  = 1.0f / 50.0f;
    const float invs50 = 0.141421356237309515f;  // 1/sqrt(50)

    float acc   = 0.0f;
    float c0acc = 0.0f;
    for (int k = 0; k < FB_; ++k) {
        int   mm   = (k * tau) % 50;
        float cosv = cospif((float)(2 * mm) / 50.0f);
        float wk   = (k == 0 || k == 25) ? 1.0f : 2.0f;
        int   o    = (h * FB_ + k) * 2 + cls;
        float coef;
        if (cls == 0) coef = wk * inv50 * cosv * base_filter[h * FB_ + k];
        else          coef = wk * invs50 * cosv;
        acc += coef * w2[j * 208 + o];
        if (j == 0) {
            if (cls == 0) c0acc += coef * (1.0f + b2[o]);
            else          c0acc += coef * (base_bias[h * FB_ + k] + b2[o]);
        }
    }
    Wp[j * 400 + m] = acc;
    if (j == 0) C0[m] = c0acc;
}

// ---------------------------------------------------------------------------
// K1: ctx[b,i] = mean over s of attr[b,s,i]  (float4, 4 rows/block)
// ---------------------------------------------------------------------------
__global__ __launch_bounds__(256)
void mean_kernel(const float* __restrict__ attr, float* __restrict__ ctx)
{
    const int g    = threadIdx.x >> 6;
    const int lane = threadIdx.x & 63;
    const int b    = blockIdx.x * 4 + g;
    const float4* p = (const float4*)(attr + (size_t)b * S_ * HID_) + lane;
    float4 s = make_float4(0.f, 0.f, 0.f, 0.f);
    #pragma unroll
    for (int t = 0; t < S_; ++t) {
        float4 v = p[t * 64];
        s.x += v.x; s.y += v.y; s.z += v.z; s.w += v.w;
    }
    const float is = 1.0f / S_;
    s.x *= is; s.y *= is; s.z *= is; s.w *= is;
    ((float4*)(ctx + (size_t)b * HID_))[lane] = s;
}

// ---------------------------------------------------------------------------
// Tiled f32 GEMM  C[M,N] = A[M,K] @ B[K,N] (+bias, optional exact-gelu)
// ---------------------------------------------------------------------------
template <int EPI>
__global__ __launch_bounds__(256)
void gemm_kernel(const float* __restrict__ A, const float* __restrict__ Bm,
                 const float* __restrict__ bias, float* __restrict__ C,
                 int M, int N, int K)
{
    __shared__ float As[64][33];
    __shared__ float Bs[32][64];
    const int tid = threadIdx.x;
    const int tx = tid & 15, ty = tid >> 4;
    const int col0 = blockIdx.x * 64;
    const int row0 = blockIdx.y * 64;

    float acc[4][4] = {};

    for (int k0 = 0; k0 < K; k0 += 32) {
        #pragma unroll
        for (int l = 0; l < 2; ++l) {
            int f = tid + l * 256;
            int r = f >> 3;
            int c4 = f & 7;
            float4 av = *(const float4*)(A + (size_t)(row0 + r) * K + k0 + c4 * 4);
            As[r][c4 * 4 + 0] = av.x; As[r][c4 * 4 + 1] = av.y;
            As[r][c4 * 4 + 2] = av.z; As[r][c4 * 4 + 3] = av.w;
        }
        #pragma unroll
        for (int l = 0; l < 2; ++l) {
            int f = tid + l * 256;
            int kr = f >> 4;
            int c4 = f & 15;
            int col = col0 + c4 * 4;
            float4 bv = make_float4(0.f, 0.f, 0.f, 0.f);
            if (col < N) bv = *(const float4*)(Bm + (size_t)(k0 + kr) * N + col);
            *(float4*)&Bs[kr][c4 * 4] = bv;
        }
        __syncthreads();
        #pragma unroll
        for (int kk = 0; kk < 32; ++kk) {
            float4 bv = *(float4*)&Bs[kk][tx * 4];
            float br[4] = {bv.x, bv.y, bv.z, bv.w};
            #pragma unroll
            for (int r = 0; r < 4; ++r) {
                float av = As[ty * 4 + r][kk];
                #pragma unroll
                for (int c = 0; c < 4; ++c)
                    acc[r][c] = fmaf(av, br[c], acc[r][c]);
            }
        }
        __syncthreads();
    }

    #pragma unroll
    for (int r = 0; r < 4; ++r) {
        int row = row0 + ty * 4 + r;
        #pragma unroll
        for (int c = 0; c < 4; ++c) {
            int col = col0 + tx * 4 + c;
            if (col < N) {
                float v = acc[r][c] + bias[col];
                if (EPI == 0)
                    v = 0.5f * v * (1.0f + erff(v * 0.70710678118654752f));
                C[(size_t)row * N + col] = v;
            }
        }
    }
}

// ---------------------------------------------------------------------------
// Compile-time-indexed circular conv helpers: every array index is a
// constexpr so x[], a[], cv[] are guaranteed register-resident (no scratch).
// ---------------------------------------------------------------------------
template <int T, int TP>
__device__ __forceinline__ float cval(const float (&cv)[26]) {
    constexpr int ci = ((T - TP) % 50 + 50) % 50;
    constexpr int dd = (ci > 25) ? (50 - ci) : ci;
    return cv[dd];
}

template <int R0, int TP, int... J>
__device__ __forceinline__ void convJ(float (&a)[CHUNK], const float (&x)[50],
                                      const float (&cv)[26],
                                      std::integer_sequence<int, J...>) {
    ((a[J] = fmaf(cval<R0 + J, TP>(cv), x[TP], a[J])), ...);
}

template <int R0, int... TPs>
__device__ __forceinline__ void convChunk(float (&a)[CHUNK], const float (&x)[50],
                                          const float (&cv)[26],
                                          std::integer_sequence<int, TPs...>) {
    (convJ<R0, TPs>(a, x, cv, std::make_integer_sequence<int, CHUNK>{}), ...);
}

// One 10-row chunk: conv + wavelet/combine/residual + LayerNorm + store.
// LN: stage a[] to LDS (coalesced, conflict-free), ONE wave per row does a
// float4 read + 6-step butterfly, writes (mu, rs); all threads normalize
// from registers. ~4x less shfl work than all-waves-all-rows butterflies.
template <int R0>
__device__ __forceinline__ void chunk_proc(const float (&x)[50], const float (&cv)[26],
                                           const float* __restrict__ vb,
                                           const float* __restrict__ cwp,
                                           float gam, float bet,
                                           float* __restrict__ outp,
                                           float (*buf)[HID_], float2* sums,
                                           int tid, int w, int lane)
{
    float a[CHUNK] = {};
    convChunk<R0>(a, x, cv, std::make_integer_sequence<int, 50>{});

    // wavelet + combine + residual (pairs p = R0/2 .. R0/2+4)
    #pragma unroll
    for (int q = 0; q < CHUNK / 2; ++q) {
        const int p = R0 / 2 + q;
        float e  = x[2 * p], o = x[2 * p + 1];
        float ap = 0.5f * (e + o);
        float dt = 0.5f * (e - o) * cwp[p * HD_];
        float fe = a[2 * q]     + rfl_f(vb[2 * p]);
        float fo = a[2 * q + 1] + rfl_f(vb[2 * p + 1]);
        a[2 * q]     = 0.7f * (ap + dt) + 0.3f * fe + e;
        a[2 * q + 1] = 0.7f * (ap - dt) + 0.3f * fo + o;
    }

    // stage rows in LDS (lane-consecutive -> conflict-free)
    #pragma unroll
    for (int j = 0; j < CHUNK; ++j) buf[j][tid] = a[j];
    __syncthreads();

    // wave w reduces rows w, w+4, w+8
    #pragma unroll
    for (int rr = 0; rr < 3; ++rr) {
        const int r = w + rr * 4;
        if (r < CHUNK) {
            float4 v = *(const float4*)&buf[r][lane * 4];
            float s  = (v.x + v.y) + (v.z + v.w);
            float qq = v.x * v.x + v.y * v.y + v.z * v.z + v.w * v.w;
            #pragma unroll
            for (int m = 1; m < 64; m <<= 1) {
                s  += __shfl_xor(s,  m, 64);
                qq += __shfl_xor(qq, m, 64);
            }
            if (lane == 0) {
                float mu  = s * (1.0f / HID_);
                float var = qq * (1.0f / HID_) - mu * mu;
                sums[r] = make_float2(mu, rsqrtf(var + 1e-12f));
            }
        }
    }
    __syncthreads();

    // normalize from registers; sums[j] is a 256-thread broadcast read
    #pragma unroll
    for (int j = 0; j < CHUNK; ++j) {
        float2 ms = sums[j];
        outp[(R0 + j) * HID_] = (a[j] - ms.x) * ms.y * gam + bet;
    }
}

// ---------------------------------------------------------------------------
// K5: fused circular-conv + wavelet + combine + residual + LayerNorm.
// One block per b; thread tid owns column tid (head = wave id).
// amdgpu_waves_per_eu(2): 256-VGPR budget so x[50]+a[10] stay resident
// (round-4: allocator chose 64 VGPR + ~17 scratch slots -> 68 MB extra
// writes; this removes the spills at a 4-waves/SIMD occupancy target).
// ---------------------------------------------------------------------------
__global__ __launch_bounds__(256)
__attribute__((amdgpu_waves_per_eu(2)))
void fused_kernel(const float* __restrict__ item,
                  const float* __restrict__ cw,     // (NH,25,64)
                  const float* __restrict__ cv,     // (B,400)
                  const float* __restrict__ gamma,
                  const float* __restrict__ beta,
                  float* __restrict__ out)
{
    __shared__ float  buf[CHUNK][HID_];   // 10 KB staging, reused per chunk
    __shared__ float2 sums[CHUNK];        // (mu, rs) per row

    const int b    = blockIdx.x;
    const int tid  = threadIdx.x;
    const int w    = tid >> 6;
    const int lane = tid & 63;
    const int wu   = __builtin_amdgcn_readfirstlane(w);

    // wave-uniform conv kernel (symmetric: only tau 0..25) -> SGPRs
    const float* cb = cv + (size_t)b * 400 + wu * 100;
    float cvr[26];
    #pragma unroll
    for (int j = 0; j < 26; ++j)
        cvr[j] = rfl_f(cb[j]);
    const float* vb = cb + 50;

    // this thread's column of x_heads
    const float* xp = item + (size_t)b * S_ * HID_ + tid;
    float x[50];
    #pragma unroll
    for (int t = 0; t < 50; ++t) x[t] = xp[t * HID_];

    const float gam = gamma[tid];
    const float bet = beta[tid];
    float* outp = out + (size_t)b * S_ * HID_ + tid;
    const float* cwp = cw + (size_t)(wu * NPAIR) * HD_ + lane;

    chunk_proc< 0>(x, cvr, vb, cwp, gam, bet, outp, buf, sums, tid, w, lane);
    chunk_proc<10>(x, cvr, vb, cwp, gam, bet, outp, buf, sums, tid, w, lane);
    chunk_proc<20>(x, cvr, vb, cwp, gam, bet, outp, buf, sums, tid, w, lane);
    chunk_proc<30>(x, cvr, vb, cwp, gam, bet, outp, buf, sums, tid, w, lane);
    chunk_proc<40>(x, cvr, vb, cwp, gam, bet, outp, buf, sums, tid, w, lane);
}

// ---------------------------------------------------------------------------
extern "C" void kernel_launch(void* const* d_in, const int* in_sizes, int n_in,
                              void* d_out, int out_size, void* d_ws, size_t ws_size,
                              hipStream_t stream)
{
    (void)in_sizes; (void)n_in; (void)out_size; (void)ws_size;
    const float* item = (const float*)d_in[0];
    const float* attr = (const float*)d_in[1];
    const float* cw   = (const float*)d_in[2];
    const float* bf   = (const float*)d_in[3];
    const float* bb   = (const float*)d_in[4];
    const float* w1   = (const float*)d_in[5];
    const float* b1   = (const float*)d_in[6];
    const float* w2   = (const float*)d_in[7];
    const float* b2   = (const float*)d_in[8];
    const float* g    = (const float*)d_in[9];
    const float* be   = (const float*)d_in[10];
    float* out = (float*)d_out;
    float* ws  = (float*)d_ws;

    float* ctx  = ws;              // 4096*256
    float* hbuf = ws + 1048576;    // 4096*256
    float* Wp   = ws + 2097152;    // 256*400
    float* C0   = ws + 2199552;    // 400
    float* cvb  = ws + 2200064;    // 4096*400

    hipLaunchKernelGGL(precompute_kernel, dim3(400), dim3(256), 0, stream,
                       bf, bb, w2, b2, Wp, C0);
    hipLaunchKernelGGL(mean_kernel, dim3(B_ / 4), dim3(256), 0, stream, attr, ctx);
    hipLaunchKernelGGL((gemm_kernel<0>), dim3(4, 64), dim3(256), 0, stream,
                       ctx, w1, b1, hbuf, B_, 256, 256);
    hipLaunchKernelGGL((gemm_kernel<1>), dim3(7, 64), dim3(256), 0, stream,
                       hbuf, Wp, C0, cvb, B_, 400, 256);
    hipLaunchKernelGGL(fused_kernel, dim3(B_), dim3(256), 0, stream,
                       item, cw, cvb, g, be, out);
}

// Round 8
// 572.218 us; speedup vs baseline: 1.5026x; 1.0321x over previous
//
#include <hip/hip_runtime.h>
#include <math.h>
#include <utility>

#define B_    4096
#define S_    50
#define HID_  256
#define NH_   4
#define HD_   64
#define FB_   26
#define NPAIR 25

// float-safe readfirstlane (the builtin is int(int); raw float use TRUNCATES)
__device__ __forceinline__ float rfl_f(float v) {
    union { float f; int i; } u;
    u.f = v;
    u.i = __builtin_amdgcn_readfirstlane(u.i);
    return u.f;
}

// ---------------------------------------------------------------------------
// P0: fold base_filter/base_bias/b2/w2 + inverse-DFT cosines + ALPHA=0.3 into
// Wp[256][400] and C0[400].  m = h*100 + cls*50 + tau.
// cls 0: c'[tau] = 0.3 * conv kernel (symmetric: c'[tau]==c'[50-tau])
// cls 1: v'[t]   = 0.3 * additive bias
// ---------------------------------------------------------------------------
__global__ void precompute_kernel(const float* __restrict__ base_filter,
                                  const float* __restrict__ base_bias,
                                  const float* __restrict__ w2,
                                  const float* __restrict__ b2,
                                  float* __restrict__ Wp,
                                  float* __restrict__ C0)
{
    const int m   = blockIdx.x;      // 0..399
    const int j   = threadIdx.x;     // 0..255
    const int h   = m / 100;
    const int rem = m % 100;
    const int cls = rem / 50;
    const int tau = rem % 50;

    const float inv50  = 0.3f / 50.0f;
    const float invs50 = 0.3f * 0.141421356237309515f;  // 0.3/sqrt(50)

    float acc   = 0.0f;
    float c0acc = 0.0f;
    for (int k = 0; k < FB_; ++k) {
        int   mm   = (k * tau) % 50;
        float cosv = cospif((float)(2 * mm) / 50.0f);
        float wk   = (k == 0 || k == 25) ? 1.0f : 2.0f;
        int   o    = (h * FB_ + k) * 2 + cls;
        float coef;
        if (cls == 0) coef = wk * inv50 * cosv * base_filter[h * FB_ + k];
        else          coef = wk * invs50 * cosv;
        acc += coef * w2[j * 208 + o];
        if (j == 0) {
            if (cls == 0) c0acc += coef * (1.0f + b2[o]);
            else          c0acc += coef * (base_bias[h * FB_ + k] + b2[o]);
        }
    }
    Wp[j * 400 + m] = acc;
    if (j == 0) C0[m] = c0acc;
}

// ---------------------------------------------------------------------------
// K1: ctx[b,i] = mean over s of attr[b,s,i]  (float4, 4 rows/block)
// ---------------------------------------------------------------------------
__global__ __launch_bounds__(256)
void mean_kernel(const float* __restrict__ attr, float* __restrict__ ctx)
{
    const int g    = threadIdx.x >> 6;
    const int lane = threadIdx.x & 63;
    const int b    = blockIdx.x * 4 + g;
    const float4* p = (const float4*)(attr + (size_t)b * S_ * HID_) + lane;
    float4 s = make_float4(0.f, 0.f, 0.f, 0.f);
    #pragma unroll
    for (int t = 0; t < S_; ++t) {
        float4 v = p[t * 64];
        s.x += v.x; s.y += v.y; s.z += v.z; s.w += v.w;
    }
    const float is = 1.0f / S_;
    s.x *= is; s.y *= is; s.z *= is; s.w *= is;
    ((float4*)(ctx + (size_t)b * HID_))[lane] = s;
}

// ---------------------------------------------------------------------------
// Tiled f32 GEMM  C[M,N] = A[M,K] @ B[K,N] (+bias, optional exact-gelu)
// 32x32 tile, 2x2 micro, 256 threads. Grids of 1024/1664 blocks (round-5's
// 64x64 tiling gave only 256/448 blocks = 1 wave/SIMD, latency exposed).
// ---------------------------------------------------------------------------
template <int EPI>
__global__ __launch_bounds__(256)
void gemm_kernel(const float* __restrict__ A, const float* __restrict__ Bm,
                 const float* __restrict__ bias, float* __restrict__ C,
                 int M, int N, int K)
{
    __shared__ float As[32][36];   // +4 pad: b128-aligned rows, conflict-free
    __shared__ float Bs[32][36];
    const int tid = threadIdx.x;
    const int tx = tid & 15, ty = tid >> 4;
    const int col0 = blockIdx.x * 32;
    const int row0 = blockIdx.y * 32;
    const int lr = tid >> 3;          // load row 0..31
    const int lc = (tid & 7) * 4;     // load col 0,4,..,28

    float acc[2][2] = {};

    for (int k0 = 0; k0 < K; k0 += 32) {
        float4 av = *(const float4*)(A + (size_t)(row0 + lr) * K + k0 + lc);
        *(float4*)&As[lr][lc] = av;
        float4 bv = make_float4(0.f, 0.f, 0.f, 0.f);
        if (col0 + lc + 4 <= N)
            bv = *(const float4*)(Bm + (size_t)(k0 + lr) * N + col0 + lc);
        *(float4*)&Bs[lr][lc] = bv;
        __syncthreads();
        #pragma unroll
        for (int kk = 0; kk < 32; ++kk) {
            float a0 = As[ty * 2][kk],     a1 = As[ty * 2 + 1][kk];
            float b0 = Bs[kk][tx * 2],     b1 = Bs[kk][tx * 2 + 1];
            acc[0][0] = fmaf(a0, b0, acc[0][0]);
            acc[0][1] = fmaf(a0, b1, acc[0][1]);
            acc[1][0] = fmaf(a1, b0, acc[1][0]);
            acc[1][1] = fmaf(a1, b1, acc[1][1]);
        }
        __syncthreads();
    }

    #pragma unroll
    for (int r = 0; r < 2; ++r) {
        int row = row0 + ty * 2 + r;
        #pragma unroll
        for (int c = 0; c < 2; ++c) {
            int col = col0 + tx * 2 + c;
            if (col < N) {
                float v = acc[r][c] + bias[col];
                if (EPI == 0)
                    v = 0.5f * v * (1.0f + erff(v * 0.70710678118654752f));
                C[(size_t)row * N + col] = v;
            }
        }
    }
}

// ---------------------------------------------------------------------------
// Streaming fused kernel: acc[50] resident, x streamed (each x loaded ONCE).
// acc[t] = v'[t] + sum_tau c'[tau] x[..] + P*e + Q*o   (wavelet+residual
// folded: P = 1.35+0.35*cw, Q = 0.35-0.35*cw; ALPHA folded into c',v').
// Compile-time indices everywhere -> no scratch; accumulators can't be
// rematerialized -> must stay in VGPRs (round-5's reload escape is closed).
// ---------------------------------------------------------------------------
template <int T, int TP>
__device__ __forceinline__ float cval(const float (&cv)[26]) {
    constexpr int ci = ((T - TP) % 50 + 50) % 50;
    constexpr int dd = (ci > 25) ? (50 - ci) : ci;
    return cv[dd];
}

template <int P, int... T>
__device__ __forceinline__ void convPairT(float (&acc)[50], float e, float o,
                                          const float (&cv)[26],
                                          std::integer_sequence<int, T...>) {
    ((acc[T] = fmaf(cval<T, 2 * P>(cv), e, acc[T])), ...);
    ((acc[T] = fmaf(cval<T, 2 * P + 1>(cv), o, acc[T])), ...);
}

template <int P>
__device__ __forceinline__ void convPair(float (&acc)[50],
                                         const float* __restrict__ xp,
                                         const float* __restrict__ cwp,
                                         const float (&cv)[26]) {
    float e   = xp[(2 * P) * HID_];
    float o   = xp[(2 * P + 1) * HID_];
    float cwv = cwp[P * HD_];
    convPairT<P>(acc, e, o, cv, std::make_integer_sequence<int, 50>{});
    float Pc = fmaf(0.35f, cwv, 1.35f);
    float Qc = fmaf(-0.35f, cwv, 0.35f);
    acc[2 * P]     = fmaf(Pc, e, acc[2 * P]);
    acc[2 * P]     = fmaf(Qc, o, acc[2 * P]);
    acc[2 * P + 1] = fmaf(Qc, e, acc[2 * P + 1]);
    acc[2 * P + 1] = fmaf(Pc, o, acc[2 * P + 1]);
}

template <int... Ps>
__device__ __forceinline__ void convAll(float (&acc)[50],
                                        const float* __restrict__ xp,
                                        const float* __restrict__ cwp,
                                        const float (&cv)[26],
                                        std::integer_sequence<int, Ps...>) {
    (convPair<Ps>(acc, xp, cwp, cv), ...);
}

// LN on rows [R0, R0+10): stage to LDS, one wave per row butterfly,
// broadcast (mu,rs), normalize from registers. 0 bank conflicts (measured r5).
template <int R0>
__device__ __forceinline__ void lnChunk(float (&acc)[50], float (*buf)[HID_],
                                        float2* sums, float gam, float bet,
                                        float* __restrict__ outp,
                                        int tid, int w, int lane)
{
    #pragma unroll
    for (int j = 0; j < 10; ++j) buf[j][tid] = acc[R0 + j];
    __syncthreads();

    #pragma unroll
    for (int rr = 0; rr < 3; ++rr) {
        const int r = w + rr * 4;
        if (r < 10) {
            float4 v = *(const float4*)&buf[r][lane * 4];
            float s  = (v.x + v.y) + (v.z + v.w);
            float qq = v.x * v.x + v.y * v.y + v.z * v.z + v.w * v.w;
            #pragma unroll
            for (int m = 1; m < 64; m <<= 1) {
                s  += __shfl_xor(s,  m, 64);
                qq += __shfl_xor(qq, m, 64);
            }
            if (lane == 0) {
                float mu  = s * (1.0f / HID_);
                float var = qq * (1.0f / HID_) - mu * mu;
                sums[r] = make_float2(mu, rsqrtf(var + 1e-12f));
            }
        }
    }
    __syncthreads();

    #pragma unroll
    for (int j = 0; j < 10; ++j) {
        float2 ms = sums[j];
        outp[(R0 + j) * HID_] = (acc[R0 + j] - ms.x) * ms.y * gam + bet;
    }
}

__global__ __launch_bounds__(256)
__attribute__((amdgpu_waves_per_eu(4)))   // VGPR cap 128: room for acc[50]+temps
void fused_kernel(const float* __restrict__ item,
                  const float* __restrict__ cw,     // (NH,25,64)
                  const float* __restrict__ cv,     // (B,400)
                  const float* __restrict__ gamma,
                  const float* __restrict__ beta,
                  float* __restrict__ out)
{
    __shared__ float  buf[10][HID_];   // 10.2 KB, reused per chunk
    __shared__ float2 sums[10];

    const int b    = blockIdx.x;
    const int tid  = threadIdx.x;
    const int w    = tid >> 6;
    const int lane = tid & 63;
    const int wu   = __builtin_amdgcn_readfirstlane(w);

    // wave-uniform conv kernel (26 vals) + bias v' (50 vals) -> SGPRs
    const float* cb = cv + (size_t)b * 400 + wu * 100;
    float cvr[26];
    #pragma unroll
    for (int j = 0; j < 26; ++j) cvr[j] = rfl_f(cb[j]);
    const float* vb = cb + 50;

    // init accumulators with v' (wave-uniform -> v_mov from SGPR)
    float acc[50];
    #pragma unroll
    for (int t = 0; t < 50; ++t) acc[t] = rfl_f(vb[t]);

    const float* xp  = item + (size_t)b * S_ * HID_ + tid;
    const float* cwp = cw + (size_t)(wu * NPAIR) * HD_ + lane;

    // stream x through conv + wavelet + residual
    convAll(acc, xp, cwp, cvr, std::make_integer_sequence<int, NPAIR>{});

    const float gam = gamma[tid];
    const float bet = beta[tid];
    float* outp = out + (size_t)b * S_ * HID_ + tid;

    lnChunk< 0>(acc, buf, sums, gam, bet, outp, tid, w, lane);
    lnChunk<10>(acc, buf, sums, gam, bet, outp, tid, w, lane);
    lnChunk<20>(acc, buf, sums, gam, bet, outp, tid, w, lane);
    lnChunk<30>(acc, buf, sums, gam, bet, outp, tid, w, lane);
    lnChunk<40>(acc, buf, sums, gam, bet, outp, tid, w, lane);
}

// ---------------------------------------------------------------------------
extern "C" void kernel_launch(void* const* d_in, const int* in_sizes, int n_in,
                              void* d_out, int out_size, void* d_ws, size_t ws_size,
                              hipStream_t stream)
{
    (void)in_sizes; (void)n_in; (void)out_size; (void)ws_size;
    const float* item = (const float*)d_in[0];
    const float* attr = (const float*)d_in[1];
    const float* cw   = (const float*)d_in[2];
    const float* bf   = (const float*)d_in[3];
    const float* bb   = (const float*)d_in[4];
    const float* w1   = (const float*)d_in[5];
    const float* b1   = (const float*)d_in[6];
    const float* w2   = (const float*)d_in[7];
    const float* b2   = (const float*)d_in[8];
    const float* g    = (const float*)d_in[9];
    const float* be   = (const float*)d_in[10];
    float* out = (float*)d_out;
    float* ws  = (float*)d_ws;

    float* ctx  = ws;              // 4096*256
    float* hbuf = ws + 1048576;    // 4096*256
    float* Wp   = ws + 2097152;    // 256*400
    float* C0   = ws + 2199552;    // 400
    float* cvb  = ws + 2200064;    // 4096*400

    hipLaunchKernelGGL(precompute_kernel, dim3(400), dim3(256), 0, stream,
                       bf, bb, w2, b2, Wp, C0);
    hipLaunchKernelGGL(mean_kernel, dim3(B_ / 4), dim3(256), 0, stream, attr, ctx);
    hipLaunchKernelGGL((gemm_kernel<0>), dim3(8, 128), dim3(256), 0, stream,
                       ctx, w1, b1, hbuf, B_, 256, 256);
    hipLaunchKernelGGL((gemm_kernel<1>), dim3(13, 128), dim3(256), 0, stream,
                       hbuf, Wp, C0, cvb, B_, 400, 256);
    hipLaunchKernelGGL(fused_kernel, dim3(B_), dim3(256), 0, stream,
                       item, cw, cvb, g, be, out);
}

// Round 9
// 570.725 us; speedup vs baseline: 1.5065x; 1.0026x over previous
//
#include <hip/hip_runtime.h>
#include <math.h>
#include <utility>

#define B_    4096
#define S_    50
#define HID_  256
#define NH_   4
#define HD_   64
#define FB_   26
#define NPAIR 25

// float-safe readfirstlane (the builtin is int(int); raw float use TRUNCATES)
__device__ __forceinline__ float rfl_f(float v) {
    union { float f; int i; } u;
    u.f = v;
    u.i = __builtin_amdgcn_readfirstlane(u.i);
    return u.f;
}

// ---------------------------------------------------------------------------
// P0: fold base_filter/base_bias/b2/w2 + inverse-DFT cosines + ALPHA=0.3 into
// Wp[256][400] and C0[400].  m = h*100 + cls*50 + tau.
// cls 0: c'[tau] = 0.3 * conv kernel (symmetric: c'[tau]==c'[50-tau])
// cls 1: v'[t]   = 0.3 * additive bias
// ---------------------------------------------------------------------------
__global__ void precompute_kernel(const float* __restrict__ base_filter,
                                  const float* __restrict__ base_bias,
                                  const float* __restrict__ w2,
                                  const float* __restrict__ b2,
                                  float* __restrict__ Wp,
                                  float* __restrict__ C0)
{
    const int m   = blockIdx.x;      // 0..399
    const int j   = threadIdx.x;     // 0..255
    const int h   = m / 100;
    const int rem = m % 100;
    const int cls = rem / 50;
    const int tau = rem % 50;

    const float inv50  = 0.3f / 50.0f;
    const float invs50 = 0.3f * 0.141421356237309515f;  // 0.3/sqrt(50)

    float acc   = 0.0f;
    float c0acc = 0.0f;
    for (int k = 0; k < FB_; ++k) {
        int   mm   = (k * tau) % 50;
        float cosv = cospif((float)(2 * mm) / 50.0f);
        float wk   = (k == 0 || k == 25) ? 1.0f : 2.0f;
        int   o    = (h * FB_ + k) * 2 + cls;
        float coef;
        if (cls == 0) coef = wk * inv50 * cosv * base_filter[h * FB_ + k];
        else          coef = wk * invs50 * cosv;
        acc += coef * w2[j * 208 + o];
        if (j == 0) {
            if (cls == 0) c0acc += coef * (1.0f + b2[o]);
            else          c0acc += coef * (base_bias[h * FB_ + k] + b2[o]);
        }
    }
    Wp[j * 400 + m] = acc;
    if (j == 0) C0[m] = c0acc;
}

// ---------------------------------------------------------------------------
// MLP kernel: mean + gelu(ctx@w1+b1) + (h@Wp+C0) in ONE dispatch.
// 512 blocks x 8 batch-rows. Phase A: ctx rows -> LDS (float4-coalesced attr
// read). Phase B: h = gelu(ctx@w1+b1), w1 streamed from L2, ctx broadcast
// from LDS. Phase C: cvb = h@Wp + C0 (cols tid and tid+256).
// Replaces mean_kernel + gemm<0> + gemm<1> (2 fewer dispatch drains, no
// ctx/hbuf global round-trips).
// ---------------------------------------------------------------------------
__global__ __launch_bounds__(256)
void mlp_kernel(const float* __restrict__ attr,
                const float* __restrict__ w1, const float* __restrict__ b1,
                const float* __restrict__ Wp, const float* __restrict__ C0,
                float* __restrict__ cvb)
{
    __shared__ float ctxL[8][HID_];   // 8 KB
    __shared__ float hL[8][HID_];     // 8 KB

    const int tid  = threadIdx.x;
    const int w    = tid >> 6;
    const int lane = tid & 63;
    const int b0   = blockIdx.x * 8;

    // ---- Phase A: ctx rows (mean over t) ----
    #pragma unroll
    for (int rr = 0; rr < 2; ++rr) {
        const int r = w + rr * 4;
        const float4* p = (const float4*)(attr + (size_t)(b0 + r) * S_ * HID_) + lane;
        float4 s = make_float4(0.f, 0.f, 0.f, 0.f);
        #pragma unroll
        for (int t = 0; t < S_; ++t) {
            float4 v = p[t * 64];
            s.x += v.x; s.y += v.y; s.z += v.z; s.w += v.w;
        }
        const float is = 1.0f / S_;
        s.x *= is; s.y *= is; s.z *= is; s.w *= is;
        *(float4*)&ctxL[r][lane * 4] = s;
    }
    __syncthreads();

    // ---- Phase B: h[r][tid] = gelu(sum_k ctx[r][k] * w1[k][tid] + b1[tid]) ----
    float h[8] = {};
    for (int k0 = 0; k0 < HID_; k0 += 4) {
        float w1v[4];
        #pragma unroll
        for (int i = 0; i < 4; ++i) w1v[i] = w1[(size_t)(k0 + i) * HID_ + tid];
        #pragma unroll
        for (int r = 0; r < 8; ++r) {
            float4 c4 = *(const float4*)&ctxL[r][k0];   // broadcast read
            h[r] = fmaf(c4.x, w1v[0], h[r]);
            h[r] = fmaf(c4.y, w1v[1], h[r]);
            h[r] = fmaf(c4.z, w1v[2], h[r]);
            h[r] = fmaf(c4.w, w1v[3], h[r]);
        }
    }
    const float b1v = b1[tid];
    #pragma unroll
    for (int r = 0; r < 8; ++r) {
        float v = h[r] + b1v;
        hL[r][tid] = 0.5f * v * (1.0f + erff(v * 0.70710678118654752f));
    }
    __syncthreads();

    // ---- Phase C: cvb[r][c] = sum_k h[r][k] * Wp[k][c] + C0[c] ----
    const int  c1   = tid + 256;
    const bool has1 = (c1 < 400);
    float a0[8] = {}, a1[8] = {};
    for (int k0 = 0; k0 < HID_; k0 += 4) {
        float wv0[4], wv1[4];
        #pragma unroll
        for (int i = 0; i < 4; ++i) {
            wv0[i] = Wp[(size_t)(k0 + i) * 400 + tid];
            wv1[i] = has1 ? Wp[(size_t)(k0 + i) * 400 + c1] : 0.f;
        }
        #pragma unroll
        for (int r = 0; r < 8; ++r) {
            float4 h4 = *(const float4*)&hL[r][k0];     // broadcast read
            a0[r] = fmaf(h4.x, wv0[0], a0[r]);
            a0[r] = fmaf(h4.y, wv0[1], a0[r]);
            a0[r] = fmaf(h4.z, wv0[2], a0[r]);
            a0[r] = fmaf(h4.w, wv0[3], a0[r]);
            a1[r] = fmaf(h4.x, wv1[0], a1[r]);
            a1[r] = fmaf(h4.y, wv1[1], a1[r]);
            a1[r] = fmaf(h4.z, wv1[2], a1[r]);
            a1[r] = fmaf(h4.w, wv1[3], a1[r]);
        }
    }
    const float c0a = C0[tid];
    const float c0b = has1 ? C0[c1] : 0.f;
    #pragma unroll
    for (int r = 0; r < 8; ++r) {
        cvb[(size_t)(b0 + r) * 400 + tid] = a0[r] + c0a;
        if (has1) cvb[(size_t)(b0 + r) * 400 + c1] = a1[r] + c0b;
    }
}

// ---------------------------------------------------------------------------
// Streaming fused kernel: acc[50] resident, x streamed (each x loaded ONCE).
// acc[t] = v'[t] + sum_tau c'[tau] x[..] + P*e + Q*o   (wavelet+residual
// folded: P = 1.35+0.35*cw, Q = 0.35-0.35*cw; ALPHA folded into c',v').
// ---------------------------------------------------------------------------
template <int T, int TP>
__device__ __forceinline__ float cval(const float (&cv)[26]) {
    constexpr int ci = ((T - TP) % 50 + 50) % 50;
    constexpr int dd = (ci > 25) ? (50 - ci) : ci;
    return cv[dd];
}

template <int P, int... T>
__device__ __forceinline__ void convPairT(float (&acc)[50], float e, float o,
                                          const float (&cv)[26],
                                          std::integer_sequence<int, T...>) {
    ((acc[T] = fmaf(cval<T, 2 * P>(cv), e, acc[T])), ...);
    ((acc[T] = fmaf(cval<T, 2 * P + 1>(cv), o, acc[T])), ...);
}

template <int P>
__device__ __forceinline__ void convPair(float (&acc)[50],
                                         const float* __restrict__ xp,
                                         const float* __restrict__ cwp,
                                         const float (&cv)[26]) {
    float e   = xp[(2 * P) * HID_];
    float o   = xp[(2 * P + 1) * HID_];
    float cwv = cwp[P * HD_];
    convPairT<P>(acc, e, o, cv, std::make_integer_sequence<int, 50>{});
    float Pc = fmaf(0.35f, cwv, 1.35f);
    float Qc = fmaf(-0.35f, cwv, 0.35f);
    acc[2 * P]     = fmaf(Pc, e, acc[2 * P]);
    acc[2 * P]     = fmaf(Qc, o, acc[2 * P]);
    acc[2 * P + 1] = fmaf(Qc, e, acc[2 * P + 1]);
    acc[2 * P + 1] = fmaf(Pc, o, acc[2 * P + 1]);
}

template <int... Ps>
__device__ __forceinline__ void convAll(float (&acc)[50],
                                        const float* __restrict__ xp,
                                        const float* __restrict__ cwp,
                                        const float (&cv)[26],
                                        std::integer_sequence<int, Ps...>) {
    (convPair<Ps>(acc, xp, cwp, cv), ...);
}

// LN on rows [R0, R0+10): stage to LDS, one wave per row butterfly,
// broadcast (mu,rs), normalize from registers. 0 bank conflicts (measured r5).
template <int R0>
__device__ __forceinline__ void lnChunk(float (&acc)[50], float (*buf)[HID_],
                                        float2* sums, float gam, float bet,
                                        float* __restrict__ outp,
                                        int tid, int w, int lane)
{
    #pragma unroll
    for (int j = 0; j < 10; ++j) buf[j][tid] = acc[R0 + j];
    __syncthreads();

    #pragma unroll
    for (int rr = 0; rr < 3; ++rr) {
        const int r = w + rr * 4;
        if (r < 10) {
            float4 v = *(const float4*)&buf[r][lane * 4];
            float s  = (v.x + v.y) + (v.z + v.w);
            float qq = v.x * v.x + v.y * v.y + v.z * v.z + v.w * v.w;
            #pragma unroll
            for (int m = 1; m < 64; m <<= 1) {
                s  += __shfl_xor(s,  m, 64);
                qq += __shfl_xor(qq, m, 64);
            }
            if (lane == 0) {
                float mu  = s * (1.0f / HID_);
                float var = qq * (1.0f / HID_) - mu * mu;
                sums[r] = make_float2(mu, rsqrtf(var + 1e-12f));
            }
        }
    }
    __syncthreads();

    #pragma unroll
    for (int j = 0; j < 10; ++j) {
        float2 ms = sums[j];
        outp[(R0 + j) * HID_] = (acc[R0 + j] - ms.x) * ms.y * gam + bet;
    }
}

__global__ __launch_bounds__(256)
__attribute__((amdgpu_waves_per_eu(4)))   // VGPR cap 128: room for acc[50]+temps
void fused_kernel(const float* __restrict__ item,
                  const float* __restrict__ cw,     // (NH,25,64)
                  const float* __restrict__ cv,     // (B,400)
                  const float* __restrict__ gamma,
                  const float* __restrict__ beta,
                  float* __restrict__ out)
{
    __shared__ float  buf[10][HID_];   // 10.2 KB, reused per chunk
    __shared__ float2 sums[10];

    const int b    = blockIdx.x;
    const int tid  = threadIdx.x;
    const int w    = tid >> 6;
    const int lane = tid & 63;
    const int wu   = __builtin_amdgcn_readfirstlane(w);

    // wave-uniform conv kernel (26 vals) + bias v' (50 vals) -> SGPRs
    const float* cb = cv + (size_t)b * 400 + wu * 100;
    float cvr[26];
    #pragma unroll
    for (int j = 0; j < 26; ++j) cvr[j] = rfl_f(cb[j]);
    const float* vb = cb + 50;

    // init accumulators with v' (wave-uniform -> v_mov from SGPR)
    float acc[50];
    #pragma unroll
    for (int t = 0; t < 50; ++t) acc[t] = rfl_f(vb[t]);

    const float* xp  = item + (size_t)b * S_ * HID_ + tid;
    const float* cwp = cw + (size_t)(wu * NPAIR) * HD_ + lane;

    // stream x through conv + wavelet + residual
    convAll(acc, xp, cwp, cvr, std::make_integer_sequence<int, NPAIR>{});

    const float gam = gamma[tid];
    const float bet = beta[tid];
    float* outp = out + (size_t)b * S_ * HID_ + tid;

    lnChunk< 0>(acc, buf, sums, gam, bet, outp, tid, w, lane);
    lnChunk<10>(acc, buf, sums, gam, bet, outp, tid, w, lane);
    lnChunk<20>(acc, buf, sums, gam, bet, outp, tid, w, lane);
    lnChunk<30>(acc, buf, sums, gam, bet, outp, tid, w, lane);
    lnChunk<40>(acc, buf, sums, gam, bet, outp, tid, w, lane);
}

// ---------------------------------------------------------------------------
extern "C" void kernel_launch(void* const* d_in, const int* in_sizes, int n_in,
                              void* d_out, int out_size, void* d_ws, size_t ws_size,
                              hipStream_t stream)
{
    (void)in_sizes; (void)n_in; (void)out_size; (void)ws_size;
    const float* item = (const float*)d_in[0];
    const float* attr = (const float*)d_in[1];
    const float* cw   = (const float*)d_in[2];
    const float* bf   = (const float*)d_in[3];
    const float* bb   = (const float*)d_in[4];
    const float* w1   = (const float*)d_in[5];
    const float* b1   = (const float*)d_in[6];
    const float* w2   = (const float*)d_in[7];
    const float* b2   = (const float*)d_in[8];
    const float* g    = (const float*)d_in[9];
    const float* be   = (const float*)d_in[10];
    float* out = (float*)d_out;
    float* ws  = (float*)d_ws;

    float* Wp  = ws;               // 256*400 = 102,400 f
    float* C0  = ws + 102400;      // 400 f
    float* cvb = ws + 102800;      // 4096*400 f  (16B-aligned offsets)

    hipLaunchKernelGGL(precompute_kernel, dim3(400), dim3(256), 0, stream,
                       bf, bb, w2, b2, Wp, C0);
    hipLaunchKernelGGL(mlp_kernel, dim3(B_ / 8), dim3(256), 0, stream,
                       attr, w1, b1, Wp, C0, cvb);
    hipLaunchKernelGGL(fused_kernel, dim3(B_), dim3(256), 0, stream,
                       item, cw, cvb, g, be, out);
}